// Round 18
// baseline (4691.696 us; speedup 1.0000x reference)
//
#include <hip/hip_runtime.h>
#include <math.h>

#define B_    8
#define N_    96
#define EMB_  768
#define HID_  384
#define GID_  1152   // 3*HID
#define CONC_ 1152   // (L+1)*HID
#define CODE_ 192
#define FEAT_ 768
#define NSL_  64     // slices per batch
#define SD_   6      // dims per slice
#define NRW_  42     // 36 gate rows + 6 M rows per layer
#define HP_   98     // history pitch (ushort elements)

__device__ __forceinline__ float sigf(float x) { return 1.0f / (1.0f + expf(-x)); }

__device__ __forceinline__ void atstf(float* p, float v) {
  __hip_atomic_store(p, v, __ATOMIC_RELAXED, __HIP_MEMORY_SCOPE_AGENT);
}
__device__ __forceinline__ float atldf(const float* p) {
  return __hip_atomic_load((float*)p, __ATOMIC_RELAXED, __HIP_MEMORY_SCOPE_AGENT);
}
__device__ __forceinline__ float dot4(float4 a, float4 b) {
  return fmaf(a.x, b.x, fmaf(a.y, b.y, fmaf(a.z, b.z, a.w * b.w)));
}
__device__ __forceinline__ unsigned short f2bf(float f) {   // RNE to bf16
  unsigned u = __float_as_uint(f);
  u += 0x7fffu + ((u >> 16) & 1u);
  return (unsigned short)(u >> 16);
}
__device__ __forceinline__ float bfu(unsigned short s) {
  return __uint_as_float(((unsigned)s) << 16);
}

// ---------------- generic GEMM: C[M,N] = act(A @ W^T + bias) ----------------
template<int RELU>
__global__ __launch_bounds__(256)
void gemm_bias(const float* __restrict__ A, int lda,
               const float* __restrict__ W,
               const float* __restrict__ bias,
               float* __restrict__ C, int ldc, int K)
{
  __shared__ float As[16][68];
  __shared__ float Bs[16][68];
  const int tid = threadIdx.x;
  const int m0 = blockIdx.y * 64;
  const int n0 = blockIdx.x * 64;
  const int lr = tid >> 2;
  const int lc = (tid & 3) * 4;
  const int ty = tid >> 4, tx = tid & 15;
  float acc[4][4] = {};
  for (int k0 = 0; k0 < K; k0 += 16) {
    float4 a4 = *(const float4*)(A + (size_t)(m0 + lr) * lda + k0 + lc);
    float4 b4 = *(const float4*)(W + (size_t)(n0 + lr) * K + k0 + lc);
    As[lc+0][lr] = a4.x; As[lc+1][lr] = a4.y; As[lc+2][lr] = a4.z; As[lc+3][lr] = a4.w;
    Bs[lc+0][lr] = b4.x; Bs[lc+1][lr] = b4.y; Bs[lc+2][lr] = b4.z; Bs[lc+3][lr] = b4.w;
    __syncthreads();
#pragma unroll
    for (int k = 0; k < 16; ++k) {
      float av[4], bv[4];
#pragma unroll
      for (int i = 0; i < 4; ++i) av[i] = As[k][ty*4+i];
#pragma unroll
      for (int j = 0; j < 4; ++j) bv[j] = Bs[k][tx*4+j];
#pragma unroll
      for (int i = 0; i < 4; ++i)
#pragma unroll
        for (int j = 0; j < 4; ++j) acc[i][j] = fmaf(av[i], bv[j], acc[i][j]);
    }
    __syncthreads();
  }
#pragma unroll
  for (int i = 0; i < 4; ++i) {
    int m = m0 + ty*4 + i;
#pragma unroll
    for (int j = 0; j < 4; ++j) {
      int n = n0 + tx*4 + j;
      float v = acc[i][j] + bias[n];
      if (RELU) v = fmaxf(v, 0.0f);
      C[(size_t)m * ldc + n] = v;
    }
  }
}

// ---- paired GEMM: z=0 -> C0 = A@W0^T+b0 ; z=1 -> C1 = A@W1^T+b1 (K=HID) ----
__global__ __launch_bounds__(256)
void gemm_bias2(const float* __restrict__ A,
                const float* __restrict__ W0, const float* __restrict__ b0,
                float* __restrict__ C0,
                const float* __restrict__ W1, const float* __restrict__ b1,
                float* __restrict__ C1)
{
  const float* W    = (blockIdx.z == 0) ? W0 : W1;
  const float* bias = (blockIdx.z == 0) ? b0 : b1;
  float*       C    = (blockIdx.z == 0) ? C0 : C1;
  __shared__ float As[16][68];
  __shared__ float Bs[16][68];
  const int tid = threadIdx.x;
  const int m0 = blockIdx.y * 64;
  const int n0 = blockIdx.x * 64;
  const int lr = tid >> 2;
  const int lc = (tid & 3) * 4;
  const int ty = tid >> 4, tx = tid & 15;
  float acc[4][4] = {};
  for (int k0 = 0; k0 < HID_; k0 += 16) {
    float4 a4 = *(const float4*)(A + (size_t)(m0 + lr) * CONC_ + k0 + lc);
    float4 b4 = *(const float4*)(W + (size_t)(n0 + lr) * HID_ + k0 + lc);
    As[lc+0][lr] = a4.x; As[lc+1][lr] = a4.y; As[lc+2][lr] = a4.z; As[lc+3][lr] = a4.w;
    Bs[lc+0][lr] = b4.x; Bs[lc+1][lr] = b4.y; Bs[lc+2][lr] = b4.z; Bs[lc+3][lr] = b4.w;
    __syncthreads();
#pragma unroll
    for (int k = 0; k < 16; ++k) {
      float av[4], bv[4];
#pragma unroll
      for (int i = 0; i < 4; ++i) av[i] = As[k][ty*4+i];
#pragma unroll
      for (int j = 0; j < 4; ++j) bv[j] = Bs[k][tx*4+j];
#pragma unroll
      for (int i = 0; i < 4; ++i)
#pragma unroll
        for (int j = 0; j < 4; ++j) acc[i][j] = fmaf(av[i], bv[j], acc[i][j]);
    }
    __syncthreads();
  }
#pragma unroll
  for (int i = 0; i < 4; ++i) {
    int m = m0 + ty*4 + i;
#pragma unroll
    for (int j = 0; j < 4; ++j) {
      int n = n0 + tx*4 + j;
      C[(size_t)m * GID_ + n] = acc[i][j] + bias[n];
    }
  }
}

// ---------- product GEMMs: G[q] = A_q @ W_q, A:[1152,384], W:[384,384] ------
__global__ __launch_bounds__(256)
void prod_kernel(const float* __restrict__ Ac, const float* __restrict__ Ap,
                 const float* __restrict__ W0, const float* __restrict__ W1,
                 float* __restrict__ G)
{
  const float* A = (blockIdx.z < 2) ? Ac : Ap;
  const float* W = (blockIdx.z & 1) ? W1 : W0;
  float* C = G + (size_t)blockIdx.z * GID_ * HID_;
  __shared__ float As[16][68];
  __shared__ float Bs[16][68];
  const int tid = threadIdx.x;
  const int m0 = blockIdx.y * 64;
  const int n0 = blockIdx.x * 64;
  const int lr = tid >> 2;
  const int lc = (tid & 3) * 4;
  const int lr2 = tid & 63, kq = tid >> 6;
  const int ty = tid >> 4, tx = tid & 15;
  float acc[4][4] = {};
  for (int k0 = 0; k0 < HID_; k0 += 16) {
    float4 a4 = *(const float4*)(A + (size_t)(m0 + lr) * HID_ + k0 + lc);
    As[lc+0][lr] = a4.x; As[lc+1][lr] = a4.y; As[lc+2][lr] = a4.z; As[lc+3][lr] = a4.w;
#pragma unroll
    for (int u = 0; u < 4; ++u) {
      int kl = kq * 4 + u;
      Bs[kl][lr2] = W[(size_t)(k0 + kl) * HID_ + n0 + lr2];
    }
    __syncthreads();
#pragma unroll
    for (int k = 0; k < 16; ++k) {
      float av[4], bv[4];
#pragma unroll
      for (int i = 0; i < 4; ++i) av[i] = As[k][ty*4+i];
#pragma unroll
      for (int j = 0; j < 4; ++j) bv[j] = Bs[k][tx*4+j];
#pragma unroll
      for (int i = 0; i < 4; ++i)
#pragma unroll
        for (int j = 0; j < 4; ++j) acc[i][j] = fmaf(av[i], bv[j], acc[i][j]);
    }
    __syncthreads();
  }
#pragma unroll
  for (int i = 0; i < 4; ++i)
#pragma unroll
    for (int j = 0; j < 4; ++j)
      C[(size_t)(m0 + ty*4 + i) * HID_ + n0 + tx*4 + j] = acc[i][j];
}

// ---------------- fused 2-layer DAG scan ----------------
// grid = 512 blocks: batch = bid>>6, slice = bid&63 (6 dims, both layers).
// Iteration t: phase A = layer-0 step t; phase B = layer-1 step t-1 (q and
// in-kernel GIc/GHp from the h0[t-1] staged in phase A). Each chain's LLC
// visibility window is covered by the opposite phase's compute.
struct Scan2P {
  const float* Hl0; float* bufC0; float* bufC1;
  float* hnX0; float* hnX1;
  const float* G0; const float* G1;
  const float* GIc; const float* GHp;        // layer-0 precomputed
  const float* bhhc0; const float* bihp0;
  const float* Wr00; const float* Wr10; const float* wk0;
  const float* Wr01; const float* Wr11; const float* wk1;
  const float* Wihc1; const float* bihc1;    // layer-1 gi rows
  const float* Whhp1; const float* bhhp1;    // layer-1 gh rows
  const float* bhhc1; const float* bihp1;
  const float* mask0; const float* mask1; const float* smask;
  float* adjB0; float* adjB1o;
};

__device__ __forceinline__ void bulk_stage(const float* src, float* stg, int tid)
{
  if (tid < NSL_) {
    const float* f_ = src + tid * SD_;
    while (__float_as_uint(atldf(f_)) == 0xFFFFFFFFu) {}
  }
  __syncthreads();
  {
    float v0 = atldf(src + tid);
    while (__float_as_uint(v0) == 0xFFFFFFFFu) v0 = atldf(src + tid);
    stg[tid] = v0;
    if (tid < HID_ - 256) {
      float v1 = atldf(src + 256 + tid);
      while (__float_as_uint(v1) == 0xFFFFFFFFu) v1 = atldf(src + 256 + tid);
      stg[256 + tid] = v1;
    }
  }
  __syncthreads();
}

template<int ENC>
__device__ __forceinline__ void make_w(
    int i, int tid, float pf_m, float* alpha, const float* s_sm,
    float* ws0, float* ws1, float* red4a, float* red4b,
    const float* shak, float* adjRow)
{
  if (ENC) {
    float ak_new = *shak;
    if (tid == 0) alpha[i - 1] = ak_new;
    float av = -3.0e38f;
    if (tid < i) {
      float ak = (tid == i - 1) ? ak_new : alpha[tid];
      av = ak - (1.0f - pf_m) * 1e30f;
    }
    float v = av;
#pragma unroll
    for (int m = 32; m; m >>= 1) v = fmaxf(v, __shfl_xor(v, m));
    if ((tid & 63) == 0) red4a[tid >> 6] = v;
    __syncthreads();
    float mx = fmaxf(fmaxf(red4a[0], red4a[1]), fmaxf(red4a[2], red4a[3]));
    float e = (tid < i) ? expf(av - mx) : 0.0f;
    v = e;
#pragma unroll
    for (int m = 32; m; m >>= 1) v += __shfl_xor(v, m);
    if ((tid & 63) == 0) red4b[tid >> 6] = v;
    __syncthreads();
    float ssum = red4b[0] + red4b[1] + red4b[2] + red4b[3];
    if (tid < N_) {
      float w = (tid < i) ? e / ssum : 0.0f;
      float sv = s_sm[tid];
      ws0[tid] = w * sv;
      ws1[tid] = w - w * sv;
      if (adjRow) adjRow[tid] = w;
    }
    __syncthreads();
  } else {
    if (tid < N_) {
      float w = (tid < i) ? -pf_m : 0.0f;
      float sv = s_sm[tid];
      ws0[tid] = w * sv;
      ws1[tid] = w - w * sv;
    }
    __syncthreads();
  }
}

__device__ __forceinline__ void hist_dots(
    const unsigned short* PA, const unsigned short* PB,
    const float* ws0, const float* ws1, float* dots, int team, int lane)
{
  float wsr0[6], wsr1[6];
#pragma unroll
  for (int k = 0; k < 6; ++k) { wsr0[k] = ws0[lane + 16*k]; wsr1[k] = ws1[lane + 16*k]; }
#pragma unroll
  for (int u = 0; u < 3; ++u) {
    const int r = team + 16 * u;
    if (r < NRW_) {
      float acc = 0.f;
#pragma unroll
      for (int k = 0; k < 6; ++k) {
        int n = lane + 16*k;
        acc = fmaf(wsr0[k], bfu(PA[r * HP_ + n]),
              fmaf(wsr1[k], bfu(PB[r * HP_ + n]), acc));
      }
#pragma unroll
      for (int mm = 8; mm; mm >>= 1) acc += __shfl_xor(acc, mm);
      if (lane == 0) dots[r] = acc;
    }
  }
}

template<int ENC>
__global__ __launch_bounds__(256, 2)
void scan2_kernel(Scan2P p)
{
  const int tid  = threadIdx.x;
  const int b    = blockIdx.x >> 6;
  const int sl   = blockIdx.x & 63;
  const int j0   = sl * SD_;
  const int team = tid >> 4, lane = tid & 15;

  __shared__ __align__(16) float stage0[HID_];
  __shared__ __align__(16) float stage1[HID_];
  __shared__ unsigned short PA0[NRW_*HP_], PB0[NRW_*HP_];
  __shared__ unsigned short PA1[NRW_*HP_], PB1[NRW_*HP_];
  __shared__ float ws0[N_], ws1[N_], s_sm[N_];
  __shared__ float alpha0[N_], alpha1[N_];
  __shared__ float dots[48];
  __shared__ float gdI[18], gdH[18];
  __shared__ float red4a[4], red4b[4];
  __shared__ float sh_ak;

  for (int k = tid; k < NRW_*HP_; k += 256) { PA0[k]=0; PB0[k]=0; PA1[k]=0; PB1[k]=0; }

  // column row-pair pointers (both layers)
  const float4 *pA0[3], *pB0[3], *pA1[3], *pB1[3];
#pragma unroll
  for (int u = 0; u < 3; ++u) {
    const int r = team + 16 * u;
    const float *A0,*B0,*A1,*B1;
    if (r < 36) {
      const int g = r / 6, jl = r % 6;
      const size_t off = (size_t)((g % 3) * HID_ + j0 + jl) * HID_;
      const float* b0 = p.G0 + (g < 3 ? 0 : 2) * (size_t)GID_ * HID_;
      const float* b1 = p.G1 + (g < 3 ? 0 : 2) * (size_t)GID_ * HID_;
      A0 = b0 + off; B0 = b0 + (size_t)GID_ * HID_ + off;
      A1 = b1 + off; B1 = b1 + (size_t)GID_ * HID_ + off;
    } else if (r < 42) {
      const int jl = r - 36;
      A0 = p.Wr00 + (size_t)(j0 + jl) * HID_; B0 = p.Wr10 + (size_t)(j0 + jl) * HID_;
      A1 = p.Wr01 + (size_t)(j0 + jl) * HID_; B1 = p.Wr11 + (size_t)(j0 + jl) * HID_;
    } else if (r == 42 && ENC) {
      A0 = p.wk0; B0 = p.wk0; A1 = p.wk1; B1 = p.wk1;
    } else {
      A0 = p.Wr00; B0 = p.Wr10; A1 = p.Wr01; B1 = p.Wr11;
    }
    pA0[u]=(const float4*)A0; pB0[u]=(const float4*)B0;
    pA1[u]=(const float4*)A1; pB1[u]=(const float4*)B1;
  }
  // layer-1 gi/gh pair pointers + row biases (18 pairs)
  const float4 *pGI[2], *pGH[2]; float bGI[2], bGH[2];
#pragma unroll
  for (int u = 0; u < 2; ++u) {
    const int r2 = team + 16 * u;
    if (r2 < 18) {
      const int g = r2 / 6, jl = r2 % 6;
      const size_t row = (size_t)(g * HID_ + j0 + jl);
      pGI[u] = (const float4*)(p.Wihc1 + row * HID_);
      pGH[u] = (const float4*)(p.Whhp1 + row * HID_);
      bGI[u] = p.bihc1[row]; bGH[u] = p.bhhp1[row];
    } else {
      pGI[u] = (const float4*)p.Wihc1; pGH[u] = (const float4*)p.Whhp1;
      bGI[u] = 0.f; bGH[u] = 0.f;
    }
  }
  float c0h0=0,c0h1=0,c0h2=0,c0i0=0,c0i1=0,c0i2=0;
  float c1h0=0,c1h1=0,c1h2=0,c1i0=0,c1i1=0,c1i2=0;
  if (tid < SD_) {
    int j = j0 + tid;
    c0h0=p.bhhc0[j]; c0h1=p.bhhc0[HID_+j]; c0h2=p.bhhc0[2*HID_+j];
    c0i0=p.bihp0[j]; c0i1=p.bihp0[HID_+j]; c0i2=p.bihp0[2*HID_+j];
    c1h0=p.bhhc1[j]; c1h1=p.bhhc1[HID_+j]; c1h2=p.bhhc1[2*HID_+j];
    c1i0=p.bihp1[j]; c1i1=p.bihp1[HID_+j]; c1i2=p.bihp1[2*HID_+j];
  }

  // node0 layer-0
  if (tid < SD_) {
    int j = j0 + tid;
    const float* gi = p.GIc + (size_t)(b * N_) * GID_;
    const float* gh = p.GHp + (size_t)(b * N_) * GID_;
    float rc = sigf(gi[j] + c0h0);
    float zc = sigf(gi[HID_ + j] + c0h1);
    float nc = tanhf(gi[2*HID_ + j] + rc * c0h2);
    float outc = (1.0f - zc) * nc;
    float rp = sigf(c0i0 + gh[j]);
    float zp = sigf(c0i1 + gh[HID_ + j]);
    float np = tanhf(c0i2 + rp * gh[2*HID_ + j]);
    float x0 = p.Hl0[(size_t)(b * N_) * CONC_ + j];
    float h0 = outc + (1.0f - zp) * np + zp * x0;
    p.bufC0[(size_t)(b * N_) * CONC_ + j] = h0;
    atstf(&p.hnX0[(size_t)(b * N_) * HID_ + j], h0);
  }
  __syncthreads();

  for (int t = 1; t <= N_; ++t) {
    const bool doA = (t < N_);
    // ======== phase A: layer-0 step t ========
    float a_gi0=0,a_gi1=0,a_gi2=0,a_gh0=0,a_gh1=0,a_gh2=0,a_q=0,a_m=0;
    if (doA) {
      if (tid < SD_) {
        int j = j0 + tid;
        const float* gi = p.GIc + ((size_t)b * N_ + t) * GID_;
        const float* gh = p.GHp + ((size_t)b * N_ + t) * GID_;
        a_gi0 = gi[j]; a_gi1 = gi[HID_ + j]; a_gi2 = gi[2*HID_ + j];
        a_gh0 = gh[j]; a_gh1 = gh[HID_ + j]; a_gh2 = gh[2*HID_ + j];
        a_q   = p.Hl0[((size_t)b * N_ + t) * CONC_ + j];
      }
      if (tid < N_) {
        a_m = p.mask0[((size_t)b * N_ + t) * N_ + tid];
        s_sm[tid] = p.smask[((size_t)b * N_ + t) * N_ + tid];
      }
    }
    bulk_stage(p.hnX0 + (size_t)(b * N_ + t - 1) * HID_, stage0, tid);
    if (doA) {
      const float4* st = (const float4*)stage0;
      float4 hr[6];
#pragma unroll
      for (int m = 0; m < 6; ++m) hr[m] = st[lane + 16*m];
#pragma unroll
      for (int u = 0; u < 3; ++u) {
        const int r = team + 16 * u;
        float a = 0.f, bv = 0.f;
#pragma unroll
        for (int m = 0; m < 6; ++m) {
          a  += dot4(pA0[u][lane + 16*m], hr[m]);
          bv += dot4(pB0[u][lane + 16*m], hr[m]);
        }
#pragma unroll
        for (int mm = 8; mm; mm >>= 1) { a += __shfl_xor(a, mm); bv += __shfl_xor(bv, mm); }
        if (lane == 0) {
          if (r < NRW_) { PA0[r*HP_ + (t-1)] = f2bf(a); PB0[r*HP_ + (t-1)] = f2bf(bv); }
          else if (ENC && r == 42) sh_ak = a;
        }
      }
      __syncthreads();
      float* adjRow = (ENC && sl == 0) ? (p.adjB0 + ((size_t)b * N_ + t) * N_) : nullptr;
      make_w<ENC>(t, tid, a_m, alpha0, s_sm, ws0, ws1, red4a, red4b, &sh_ak, adjRow);
      hist_dots(PA0, PB0, ws0, ws1, dots, team, lane);
      __syncthreads();
      if (tid < SD_) {
        int j = j0 + tid;
        float Mj = dots[36 + tid];
        float rc = sigf(a_gi0 + dots[tid] + c0h0);
        float zc = sigf(a_gi1 + dots[6 + tid] + c0h1);
        float nc = tanhf(a_gi2 + rc * (dots[12 + tid] + c0h2));
        float outc = (1.0f - zc) * nc + zc * Mj;
        float rp = sigf(dots[18 + tid] + c0i0 + a_gh0);
        float zp = sigf(dots[24 + tid] + c0i1 + a_gh1);
        float np = tanhf(dots[30 + tid] + c0i2 + rp * a_gh2);
        float hv = outc + (1.0f - zp) * np + zp * a_q;
        p.bufC0[((size_t)b * N_ + t) * CONC_ + j] = hv;
        atstf(&p.hnX0[((size_t)b * N_ + t) * HID_ + j], hv);
      }
    }
    // ======== phase B: layer-1 step t-1 (q = h0[t-1] in stage0) ========
    {
      const float4* st = (const float4*)stage0;
      float4 hr[6];
#pragma unroll
      for (int m = 0; m < 6; ++m) hr[m] = st[lane + 16*m];
#pragma unroll
      for (int u = 0; u < 2; ++u) {
        const int r2 = team + 16 * u;
        float a = 0.f, bv = 0.f;
#pragma unroll
        for (int m = 0; m < 6; ++m) {
          a  += dot4(pGI[u][lane + 16*m], hr[m]);
          bv += dot4(pGH[u][lane + 16*m], hr[m]);
        }
#pragma unroll
        for (int mm = 8; mm; mm >>= 1) { a += __shfl_xor(a, mm); bv += __shfl_xor(bv, mm); }
        if (lane == 0 && r2 < 18) { gdI[r2] = a + bGI[u]; gdH[r2] = bv + bGH[u]; }
      }
    }
    if (t == 1) {
      __syncthreads();
      if (tid < SD_) {          // layer-1 node0
        int j = j0 + tid;
        float rc = sigf(gdI[tid] + c1h0);
        float zc = sigf(gdI[6 + tid] + c1h1);
        float nc = tanhf(gdI[12 + tid] + rc * c1h2);
        float outc = (1.0f - zc) * nc;
        float rp = sigf(c1i0 + gdH[tid]);
        float zp = sigf(c1i1 + gdH[6 + tid]);
        float np = tanhf(c1i2 + rp * gdH[12 + tid]);
        float x0 = stage0[j];
        float hv = outc + (1.0f - zp) * np + zp * x0;
        p.bufC1[(size_t)(b * N_) * CONC_ + j] = hv;
        atstf(&p.hnX1[(size_t)(b * N_) * HID_ + j], hv);
      }
      __syncthreads();
    } else {
      const int i1 = t - 1;
      float b_m = 0.f;
      if (tid < N_) {
        b_m = p.mask1[((size_t)b * N_ + i1) * N_ + tid];
        s_sm[tid] = p.smask[((size_t)b * N_ + i1) * N_ + tid];
      }
      bulk_stage(p.hnX1 + (size_t)(b * N_ + t - 2) * HID_, stage1, tid);
      const float4* st1 = (const float4*)stage1;
      float4 hr[6];
#pragma unroll
      for (int m = 0; m < 6; ++m) hr[m] = st1[lane + 16*m];
#pragma unroll
      for (int u = 0; u < 3; ++u) {
        const int r = team + 16 * u;
        float a = 0.f, bv = 0.f;
#pragma unroll
        for (int m = 0; m < 6; ++m) {
          a  += dot4(pA1[u][lane + 16*m], hr[m]);
          bv += dot4(pB1[u][lane + 16*m], hr[m]);
        }
#pragma unroll
        for (int mm = 8; mm; mm >>= 1) { a += __shfl_xor(a, mm); bv += __shfl_xor(bv, mm); }
        if (lane == 0) {
          if (r < NRW_) { PA1[r*HP_ + (t-2)] = f2bf(a); PB1[r*HP_ + (t-2)] = f2bf(bv); }
          else if (ENC && r == 42) sh_ak = a;
        }
      }
      __syncthreads();
      float* adjRow1 = (ENC && sl == 0) ? (p.adjB1o + ((size_t)b * N_ + i1) * N_) : nullptr;
      make_w<ENC>(i1, tid, b_m, alpha1, s_sm, ws0, ws1, red4a, red4b, &sh_ak, adjRow1);
      hist_dots(PA1, PB1, ws0, ws1, dots, team, lane);
      __syncthreads();
      if (tid < SD_) {
        int j = j0 + tid;
        float Mj = dots[36 + tid];
        float rc = sigf(gdI[tid] + dots[tid] + c1h0);
        float zc = sigf(gdI[6 + tid] + dots[6 + tid] + c1h1);
        float nc = tanhf(gdI[12 + tid] + rc * (dots[12 + tid] + c1h2));
        float outc = (1.0f - zc) * nc + zc * Mj;
        float rp = sigf(dots[18 + tid] + c1i0 + gdH[tid]);
        float zp = sigf(dots[24 + tid] + c1i1 + gdH[6 + tid]);
        float np = tanhf(dots[30 + tid] + c1i2 + rp * gdH[12 + tid]);
        float q1 = stage0[j];
        float hv = outc + (1.0f - zp) * np + zp * q1;
        p.bufC1[((size_t)b * N_ + i1) * CONC_ + j] = hv;
        atstf(&p.hnX1[((size_t)b * N_ + i1) * HID_ + j], hv);
      }
      __syncthreads();
    }
  }
}

// ---------------- feature_map = I - adjB2 (row 0 implicit 0) ----------------
__global__ __launch_bounds__(256)
void fmap_kernel(const float* __restrict__ adjB2, float* __restrict__ out)
{
  int idx = blockIdx.x * 256 + threadIdx.x;
  if (idx < B_ * N_ * N_) {
    int j = idx % N_;
    int i = (idx / N_) % N_;
    float a = (i == 0) ? 0.0f : adjB2[idx];
    out[idx] = ((i == j) ? 1.0f : 0.0f) - a;
  }
}

// ---------------- orchestration ----------------
extern "C" void kernel_launch(void* const* d_in, const int* in_sizes, int n_in,
                              void* d_out, int out_size, void* d_ws, size_t ws_size,
                              hipStream_t stream)
{
  (void)in_sizes; (void)n_in; (void)out_size; (void)ws_size;
  const float* features     = (const float*)d_in[0];
  const float* adj          = (const float*)d_in[1];
  const float* s_mask       = (const float*)d_in[2];
  const float* enc_fc1_W    = (const float*)d_in[5];
  const float* enc_fc1_b    = (const float*)d_in[6];
  const float* enc_gat_w    = (const float*)d_in[7];
  const float* enc_Wr0      = (const float*)d_in[9];
  const float* enc_Wr1      = (const float*)d_in[10];
  const float* enc_gruc_Wih = (const float*)d_in[11];
  const float* enc_gruc_Whh = (const float*)d_in[12];
  const float* enc_gruc_bih = (const float*)d_in[13];
  const float* enc_gruc_bhh = (const float*)d_in[14];
  const float* enc_grup_Wih = (const float*)d_in[15];
  const float* enc_grup_Whh = (const float*)d_in[16];
  const float* enc_grup_bih = (const float*)d_in[17];
  const float* enc_grup_bhh = (const float*)d_in[18];
  const float* enc_mlp_W0   = (const float*)d_in[19];
  const float* enc_mlp_b0   = (const float*)d_in[20];
  const float* enc_mlp_W1   = (const float*)d_in[21];
  const float* enc_mlp_b1   = (const float*)d_in[22];
  const float* dec_fc1_W    = (const float*)d_in[23];
  const float* dec_fc1_b    = (const float*)d_in[24];
  const float* dec_Wr0      = (const float*)d_in[25];
  const float* dec_Wr1      = (const float*)d_in[26];
  const float* dec_gruc_Wih = (const float*)d_in[27];
  const float* dec_gruc_Whh = (const float*)d_in[28];
  const float* dec_gruc_bih = (const float*)d_in[29];
  const float* dec_gruc_bhh = (const float*)d_in[30];
  const float* dec_grup_Wih = (const float*)d_in[31];
  const float* dec_grup_Whh = (const float*)d_in[32];
  const float* dec_grup_bih = (const float*)d_in[33];
  const float* dec_grup_bhh = (const float*)d_in[34];
  const float* dec_mlp_W0   = (const float*)d_in[35];
  const float* dec_mlp_b0   = (const float*)d_in[36];
  const float* dec_mlp_W1   = (const float*)d_in[37];
  const float* dec_mlp_b1   = (const float*)d_in[38];

  float* ws = (float*)d_ws;
  size_t o = 0;
  float* Hse   = ws + o; o += (size_t)B_ * N_ * CONC_;
  float* Hsd   = ws + o; o += (size_t)B_ * N_ * CONC_;
  float* GIc   = ws + o; o += (size_t)B_ * N_ * GID_;
  float* GHp   = ws + o; o += (size_t)B_ * N_ * GID_;
  float* adjB1 = ws + o; o += (size_t)B_ * N_ * N_;
  float* adjB2 = ws + o; o += (size_t)B_ * N_ * N_;
  float* fU    = ws + o; o += (size_t)B_ * N_ * CODE_;
  float* Tmp   = ws + o; o += (size_t)B_ * N_ * HID_;
  float* hnX4  = ws + o; o += (size_t)4 * B_ * N_ * HID_;
  float* Gbuf  = ws + o; o += (size_t)8 * GID_ * HID_;
  const size_t hn_elems = (size_t)B_ * N_ * HID_;
  const size_t Gly = (size_t)4 * GID_ * HID_;

  const dim3 blk(256);
  float* logits = (float*)d_out;
  float* fmap   = (float*)d_out + (size_t)B_ * N_ * FEAT_;

  hipMemsetAsync(hnX4, 0xFF, 4 * hn_elems * sizeof(float), stream);

  // encoder fc1
  gemm_bias<1><<<dim3(6, 12), blk, 0, stream>>>(features, EMB_, enc_fc1_W, enc_fc1_b,
                                                Hse, CONC_, EMB_);
  // ---- encoder pair ----
  gemm_bias2<<<dim3(18, 12, 2), blk, 0, stream>>>(Hse,
      enc_gruc_Wih, enc_gruc_bih, GIc, enc_grup_Whh, enc_grup_bhh, GHp);
  prod_kernel<<<dim3(6, 18, 4), blk, 0, stream>>>(
      enc_gruc_Whh, enc_grup_Wih, enc_Wr0, enc_Wr1, Gbuf);
  prod_kernel<<<dim3(6, 18, 4), blk, 0, stream>>>(
      enc_gruc_Whh + (size_t)GID_ * HID_, enc_grup_Wih + (size_t)GID_ * HID_,
      enc_Wr0 + (size_t)HID_ * HID_, enc_Wr1 + (size_t)HID_ * HID_, Gbuf + Gly);
  {
    Scan2P p;
    p.Hl0 = Hse; p.bufC0 = Hse + HID_; p.bufC1 = Hse + 2 * HID_;
    p.hnX0 = hnX4; p.hnX1 = hnX4 + hn_elems;
    p.G0 = Gbuf; p.G1 = Gbuf + Gly;
    p.GIc = GIc; p.GHp = GHp;
    p.bhhc0 = enc_gruc_bhh; p.bihp0 = enc_grup_bih;
    p.Wr00 = enc_Wr0; p.Wr10 = enc_Wr1; p.wk0 = enc_gat_w + HID_;
    p.Wr01 = enc_Wr0 + (size_t)HID_ * HID_; p.Wr11 = enc_Wr1 + (size_t)HID_ * HID_;
    p.wk1 = enc_gat_w + 3 * HID_;
    p.Wihc1 = enc_gruc_Wih + (size_t)GID_ * HID_; p.bihc1 = enc_gruc_bih + GID_;
    p.Whhp1 = enc_grup_Whh + (size_t)GID_ * HID_; p.bhhp1 = enc_grup_bhh + GID_;
    p.bhhc1 = enc_gruc_bhh + GID_; p.bihp1 = enc_grup_bih + GID_;
    p.mask0 = adj; p.mask1 = adj; p.smask = s_mask;
    p.adjB0 = adjB1; p.adjB1o = adjB2;
    scan2_kernel<1><<<dim3(512), blk, 0, stream>>>(p);
  }
  // encoder MLP -> fU
  gemm_bias<1><<<dim3(6, 12), blk, 0, stream>>>(Hse, CONC_, enc_mlp_W0, enc_mlp_b0,
                                                Tmp, HID_, CONC_);
  gemm_bias<0><<<dim3(3, 12), blk, 0, stream>>>(Tmp, HID_, enc_mlp_W1, enc_mlp_b1,
                                                fU, CODE_, HID_);
  // decoder fc1
  gemm_bias<1><<<dim3(6, 12), blk, 0, stream>>>(fU, CODE_, dec_fc1_W, dec_fc1_b,
                                                Hsd, CONC_, CODE_);
  // ---- decoder pair ----
  gemm_bias2<<<dim3(18, 12, 2), blk, 0, stream>>>(Hsd,
      dec_gruc_Wih, dec_gruc_bih, GIc, dec_grup_Whh, dec_grup_bhh, GHp);
  prod_kernel<<<dim3(6, 18, 4), blk, 0, stream>>>(
      dec_gruc_Whh, dec_grup_Wih, dec_Wr0, dec_Wr1, Gbuf);
  prod_kernel<<<dim3(6, 18, 4), blk, 0, stream>>>(
      dec_gruc_Whh + (size_t)GID_ * HID_, dec_grup_Wih + (size_t)GID_ * HID_,
      dec_Wr0 + (size_t)HID_ * HID_, dec_Wr1 + (size_t)HID_ * HID_, Gbuf + Gly);
  {
    Scan2P p;
    p.Hl0 = Hsd; p.bufC0 = Hsd + HID_; p.bufC1 = Hsd + 2 * HID_;
    p.hnX0 = hnX4 + 2 * hn_elems; p.hnX1 = hnX4 + 3 * hn_elems;
    p.G0 = Gbuf; p.G1 = Gbuf + Gly;
    p.GIc = GIc; p.GHp = GHp;
    p.bhhc0 = dec_gruc_bhh; p.bihp0 = dec_grup_bih;
    p.Wr00 = dec_Wr0; p.Wr10 = dec_Wr1; p.wk0 = nullptr;
    p.Wr01 = dec_Wr0 + (size_t)HID_ * HID_; p.Wr11 = dec_Wr1 + (size_t)HID_ * HID_;
    p.wk1 = nullptr;
    p.Wihc1 = dec_gruc_Wih + (size_t)GID_ * HID_; p.bihc1 = dec_gruc_bih + GID_;
    p.Whhp1 = dec_grup_Whh + (size_t)GID_ * HID_; p.bhhp1 = dec_grup_bhh + GID_;
    p.bhhc1 = dec_gruc_bhh + GID_; p.bihp1 = dec_grup_bih + GID_;
    p.mask0 = adjB1; p.mask1 = adjB2; p.smask = s_mask;
    p.adjB0 = nullptr; p.adjB1o = nullptr;
    scan2_kernel<0><<<dim3(512), blk, 0, stream>>>(p);
  }
  // decoder MLP -> logits
  gemm_bias<1><<<dim3(6, 12), blk, 0, stream>>>(Hsd, CONC_, dec_mlp_W0, dec_mlp_b0,
                                                Tmp, HID_, CONC_);
  gemm_bias<0><<<dim3(12, 12), blk, 0, stream>>>(Tmp, HID_, dec_mlp_W1, dec_mlp_b1,
                                                 logits, FEAT_, HID_);
  // feature_map
  fmap_kernel<<<dim3((B_ * N_ * N_ + 255) / 256), blk, 0, stream>>>(adjB2, fmap);
}

// Round 19
// 1899.841 us; speedup vs baseline: 2.4695x; 2.4695x over previous
//
#include <hip/hip_runtime.h>
#include <math.h>

#define B_    8
#define N_    96
#define EMB_  768
#define HID_  384
#define GID_  1152   // 3*HID
#define CONC_ 1152   // (L+1)*HID
#define CODE_ 192
#define FEAT_ 768
#define NSL_  64     // slices per batch
#define SD_   6      // dims per slice
#define NRW_  42     // 36 gate rows + 6 M rows (history rows per block)

__device__ __forceinline__ float sigf(float x) { return 1.0f / (1.0f + expf(-x)); }

// LLC-coherent (agent-scope) relaxed atomic accessors (proven visibility path).
__device__ __forceinline__ void atstf(float* p, float v) {
  __hip_atomic_store(p, v, __ATOMIC_RELAXED, __HIP_MEMORY_SCOPE_AGENT);
}
__device__ __forceinline__ float atldf(const float* p) {
  return __hip_atomic_load((float*)p, __ATOMIC_RELAXED, __HIP_MEMORY_SCOPE_AGENT);
}
__device__ __forceinline__ float dot4(float4 a, float4 b) {
  return fmaf(a.x, b.x, fmaf(a.y, b.y, fmaf(a.z, b.z, a.w * b.w)));
}

// ---------------- generic GEMM: C[M,N] = act(A @ W^T + bias) ----------------
template<int RELU>
__global__ __launch_bounds__(256)
void gemm_bias(const float* __restrict__ A, int lda,
               const float* __restrict__ W,
               const float* __restrict__ bias,
               float* __restrict__ C, int ldc, int K)
{
  __shared__ float As[16][68];
  __shared__ float Bs[16][68];
  const int tid = threadIdx.x;
  const int m0 = blockIdx.y * 64;
  const int n0 = blockIdx.x * 64;
  const int lr = tid >> 2;
  const int lc = (tid & 3) * 4;
  const int ty = tid >> 4, tx = tid & 15;
  float acc[4][4] = {};
  for (int k0 = 0; k0 < K; k0 += 16) {
    float4 a4 = *(const float4*)(A + (size_t)(m0 + lr) * lda + k0 + lc);
    float4 b4 = *(const float4*)(W + (size_t)(n0 + lr) * K + k0 + lc);
    As[lc+0][lr] = a4.x; As[lc+1][lr] = a4.y; As[lc+2][lr] = a4.z; As[lc+3][lr] = a4.w;
    Bs[lc+0][lr] = b4.x; Bs[lc+1][lr] = b4.y; Bs[lc+2][lr] = b4.z; Bs[lc+3][lr] = b4.w;
    __syncthreads();
#pragma unroll
    for (int k = 0; k < 16; ++k) {
      float av[4], bv[4];
#pragma unroll
      for (int i = 0; i < 4; ++i) av[i] = As[k][ty*4+i];
#pragma unroll
      for (int j = 0; j < 4; ++j) bv[j] = Bs[k][tx*4+j];
#pragma unroll
      for (int i = 0; i < 4; ++i)
#pragma unroll
        for (int j = 0; j < 4; ++j) acc[i][j] = fmaf(av[i], bv[j], acc[i][j]);
    }
    __syncthreads();
  }
#pragma unroll
  for (int i = 0; i < 4; ++i) {
    int m = m0 + ty*4 + i;
#pragma unroll
    for (int j = 0; j < 4; ++j) {
      int n = n0 + tx*4 + j;
      float v = acc[i][j] + bias[n];
      if (RELU) v = fmaxf(v, 0.0f);
      C[(size_t)m * ldc + n] = v;
    }
  }
}

// ---- paired GEMM: z=0 -> C0 = A@W0^T+b0 ; z=1 -> C1 = A@W1^T+b1 (K=HID) ----
__global__ __launch_bounds__(256)
void gemm_bias2(const float* __restrict__ A,
                const float* __restrict__ W0, const float* __restrict__ b0,
                float* __restrict__ C0,
                const float* __restrict__ W1, const float* __restrict__ b1,
                float* __restrict__ C1)
{
  const float* W    = (blockIdx.z == 0) ? W0 : W1;
  const float* bias = (blockIdx.z == 0) ? b0 : b1;
  float*       C    = (blockIdx.z == 0) ? C0 : C1;
  __shared__ float As[16][68];
  __shared__ float Bs[16][68];
  const int tid = threadIdx.x;
  const int m0 = blockIdx.y * 64;
  const int n0 = blockIdx.x * 64;
  const int lr = tid >> 2;
  const int lc = (tid & 3) * 4;
  const int ty = tid >> 4, tx = tid & 15;
  float acc[4][4] = {};
  for (int k0 = 0; k0 < HID_; k0 += 16) {
    float4 a4 = *(const float4*)(A + (size_t)(m0 + lr) * CONC_ + k0 + lc);
    float4 b4 = *(const float4*)(W + (size_t)(n0 + lr) * HID_ + k0 + lc);
    As[lc+0][lr] = a4.x; As[lc+1][lr] = a4.y; As[lc+2][lr] = a4.z; As[lc+3][lr] = a4.w;
    Bs[lc+0][lr] = b4.x; Bs[lc+1][lr] = b4.y; Bs[lc+2][lr] = b4.z; Bs[lc+3][lr] = b4.w;
    __syncthreads();
#pragma unroll
    for (int k = 0; k < 16; ++k) {
      float av[4], bv[4];
#pragma unroll
      for (int i = 0; i < 4; ++i) av[i] = As[k][ty*4+i];
#pragma unroll
      for (int j = 0; j < 4; ++j) bv[j] = Bs[k][tx*4+j];
#pragma unroll
      for (int i = 0; i < 4; ++i)
#pragma unroll
        for (int j = 0; j < 4; ++j) acc[i][j] = fmaf(av[i], bv[j], acc[i][j]);
    }
    __syncthreads();
  }
#pragma unroll
  for (int i = 0; i < 4; ++i) {
    int m = m0 + ty*4 + i;
#pragma unroll
    for (int j = 0; j < 4; ++j) {
      int n = n0 + tx*4 + j;
      C[(size_t)m * GID_ + n] = acc[i][j] + bias[n];
    }
  }
}

// ---------- product GEMMs: G[q] = A_q @ W_q, A:[1152,384], W:[384,384] ------
// q = blockIdx.z: 0:Whhc@Wr0 1:Whhc@Wr1 2:Wihp@Wr0 3:Wihp@Wr1
__global__ __launch_bounds__(256)
void prod_kernel(const float* __restrict__ Ac, const float* __restrict__ Ap,
                 const float* __restrict__ W0, const float* __restrict__ W1,
                 float* __restrict__ G)
{
  const float* A = (blockIdx.z < 2) ? Ac : Ap;
  const float* W = (blockIdx.z & 1) ? W1 : W0;
  float* C = G + (size_t)blockIdx.z * GID_ * HID_;
  __shared__ float As[16][68];
  __shared__ float Bs[16][68];
  const int tid = threadIdx.x;
  const int m0 = blockIdx.y * 64;
  const int n0 = blockIdx.x * 64;
  const int lr = tid >> 2;
  const int lc = (tid & 3) * 4;
  const int lr2 = tid & 63, kq = tid >> 6;
  const int ty = tid >> 4, tx = tid & 15;
  float acc[4][4] = {};
  for (int k0 = 0; k0 < HID_; k0 += 16) {
    float4 a4 = *(const float4*)(A + (size_t)(m0 + lr) * HID_ + k0 + lc);
    As[lc+0][lr] = a4.x; As[lc+1][lr] = a4.y; As[lc+2][lr] = a4.z; As[lc+3][lr] = a4.w;
#pragma unroll
    for (int u = 0; u < 4; ++u) {
      int kl = kq * 4 + u;
      Bs[kl][lr2] = W[(size_t)(k0 + kl) * HID_ + n0 + lr2];
    }
    __syncthreads();
#pragma unroll
    for (int k = 0; k < 16; ++k) {
      float av[4], bv[4];
#pragma unroll
      for (int i = 0; i < 4; ++i) av[i] = As[k][ty*4+i];
#pragma unroll
      for (int j = 0; j < 4; ++j) bv[j] = Bs[k][tx*4+j];
#pragma unroll
      for (int i = 0; i < 4; ++i)
#pragma unroll
        for (int j = 0; j < 4; ++j) acc[i][j] = fmaf(av[i], bv[j], acc[i][j]);
    }
    __syncthreads();
  }
#pragma unroll
  for (int i = 0; i < 4; ++i)
#pragma unroll
    for (int j = 0; j < 4; ++j)
      C[(size_t)(m0 + ty*4 + i) * HID_ + n0 + tx*4 + j] = acc[i][j];
}

// ---------------- DAG scan kernel ----------------
// grid = 512 blocks: batch = blockIdx>>6, slice = blockIdx&63 (6 dims each).
// ONE exchange per step (hn all-gather); gates+M via G-product rows and
// incremental per-block history PA/PB. Per-scan private hnX (no mid-stream
// re-poison). Softmax uses split red4a/red4b (3 barriers, not 4).
struct ScanP {
  const float* Hl;      // q rows, stride CONC_
  float*       bufC;    // cached output rows, stride CONC_
  float*       hnX;     // [8,96,384] exchange (sentinel-filled, atomics)
  const float* G;       // [4][1152,384] products for this scan
  const float* GIc;     // [768,1152] q@Wih_c^T + bih_c
  const float* GHp;     // [768,1152] q@Whh_p^T + bhh_p
  const float* bhhc;    // [1152]
  const float* bihp;    // [1152]
  const float* Wr0;     // [384,384]
  const float* Wr1;     // [384,384]
  const float* wk;      // [384] (enc only)
  const float* mask;    // enc: adj; dec: adjB (negated use)
  const float* smask;   // [8,96,96]
  float*       adjB;    // enc output
};

template<int ENC>
__global__ __launch_bounds__(256, 2)
void scan_kernel(ScanP p)
{
  const int tid  = threadIdx.x;
  const int b    = blockIdx.x >> 6;
  const int sl   = blockIdx.x & 63;
  const int j0   = sl * SD_;
  const int team = tid >> 4, lane = tid & 15;

  __shared__ __align__(16) float stage[HID_];
  __shared__ float ws0[N_], ws1[N_], s_sm[N_];
  __shared__ float alpha[N_];
  __shared__ float dots[48];
  __shared__ float red4a[4], red4b[4];
  __shared__ float sh_aknew;
  __shared__ float PA[NRW_ * 97];
  __shared__ float PB[NRW_ * 97];

  // zero history so the unguarded dot loop multiplies 0*0 beyond column i-1
  for (int k = tid; k < NRW_ * 97; k += 256) { PA[k] = 0.f; PB[k] = 0.f; }

  // ---- hoist the block's 48 virtual row-pairs into registers ----
  float4 wAr[3][6], wBr[3][6];
#pragma unroll
  for (int u = 0; u < 3; ++u) {
    const int r = team + 16 * u;
    const float *Aptr, *Bptr;
    if (r < 36) {
      const int g = r / 6, jl = r % 6;
      const size_t off = (size_t)((g % 3) * HID_ + j0 + jl) * HID_;
      const float* base = p.G + (g < 3 ? 0 : 2) * (size_t)GID_ * HID_;
      Aptr = base + off;
      Bptr = base + (size_t)GID_ * HID_ + off;
    } else if (r < 42) {
      const int jl = r - 36;
      Aptr = p.Wr0 + (size_t)(j0 + jl) * HID_;
      Bptr = p.Wr1 + (size_t)(j0 + jl) * HID_;
    } else if (r == 42 && ENC) {
      Aptr = p.wk; Bptr = p.wk;
    } else {
      Aptr = p.Wr0; Bptr = p.Wr1;   // dummy rows, results unused
    }
#pragma unroll
    for (int m = 0; m < 6; ++m) {
      wAr[u][m] = ((const float4*)Aptr)[lane + 16*m];
      wBr[u][m] = ((const float4*)Bptr)[lane + 16*m];
    }
  }
  float bh0=0, bh1=0, bh2=0, bi0=0, bi1=0, bi2=0;
  if (tid < SD_) {
    int j = j0 + tid;
    bh0 = p.bhhc[j]; bh1 = p.bhhc[HID_ + j]; bh2 = p.bhhc[2*HID_ + j];
    bi0 = p.bihp[j]; bi1 = p.bihp[HID_ + j]; bi2 = p.bihp[2*HID_ + j];
  }

#define BULK_STAGE(SRC)                                                      \
  do {                                                                       \
    if (tid < NSL_) {                                                        \
      const float* f_ = (SRC) + tid * SD_;                                   \
      while (__float_as_uint(atldf(f_)) == 0xFFFFFFFFu) {}                   \
    }                                                                        \
    __syncthreads();                                                         \
    {                                                                        \
      float v0 = atldf((SRC) + tid);                                         \
      while (__float_as_uint(v0) == 0xFFFFFFFFu) v0 = atldf((SRC) + tid);    \
      stage[tid] = v0;                                                       \
      if (tid < HID_ - 256) {                                                \
        float v1 = atldf((SRC) + 256 + tid);                                 \
        while (__float_as_uint(v1) == 0xFFFFFFFFu)                           \
          v1 = atldf((SRC) + 256 + tid);                                     \
        stage[256 + tid] = v1;                                               \
      }                                                                      \
    }                                                                        \
    __syncthreads();                                                         \
  } while (0)

  // ---- node 0 ----
  if (tid < SD_) {
    int j = j0 + tid;
    const float* gi = p.GIc + (size_t)(b * N_) * GID_;
    const float* gh = p.GHp + (size_t)(b * N_) * GID_;
    float rc = sigf(gi[j] + bh0);
    float zc = sigf(gi[HID_ + j] + bh1);
    float nc = tanhf(gi[2*HID_ + j] + rc * bh2);
    float outc = (1.0f - zc) * nc;
    float rp = sigf(bi0 + gh[j]);
    float zp = sigf(bi1 + gh[HID_ + j]);
    float np = tanhf(bi2 + rp * gh[2*HID_ + j]);
    float x0 = p.Hl[(size_t)(b * N_) * CONC_ + j];
    float h0 = outc + (1.0f - zp) * np + zp * x0;
    p.bufC[(size_t)(b * N_) * CONC_ + j] = h0;
    atstf(&p.hnX[(size_t)(b * N_) * HID_ + j], h0);
  }
  __syncthreads();

  for (int i = 1; i < N_; ++i) {
    // ---- prefetch step-i operands (hide under hn flight) ----
    float pf_gi0=0, pf_gi1=0, pf_gi2=0, pf_gh0=0, pf_gh1=0, pf_gh2=0, pf_q=0;
    if (tid < SD_) {
      int j = j0 + tid;
      const float* gi = p.GIc + ((size_t)b * N_ + i) * GID_;
      const float* gh = p.GHp + ((size_t)b * N_ + i) * GID_;
      pf_gi0 = gi[j]; pf_gi1 = gi[HID_ + j]; pf_gi2 = gi[2*HID_ + j];
      pf_gh0 = gh[j]; pf_gh1 = gh[HID_ + j]; pf_gh2 = gh[2*HID_ + j];
      pf_q   = p.Hl[((size_t)b * N_ + i) * CONC_ + j];
    }
    float pf_mrow = 0.0f;
    if (tid < N_) {
      pf_mrow = p.mask[((size_t)b * N_ + i) * N_ + tid];
      s_sm[tid] = p.smask[((size_t)b * N_ + i) * N_ + tid];
    }

    // ---- ONE exchange: wait + stage hn[i-1] ----
    const float* srcH = p.hnX + (size_t)(b * N_ + (i - 1)) * HID_;
    BULK_STAGE(srcH);
    const float4* st4 = (const float4*)stage;
    float4 hreg[6];
#pragma unroll
    for (int m = 0; m < 6; ++m) hreg[m] = st4[lane + 16*m];

    // ---- append history column: PA/PB[r][i-1] = A_r@h, B_r@h ----
#pragma unroll
    for (int u = 0; u < 3; ++u) {
      const int r = team + 16 * u;
      float a = 0.f, bv = 0.f;
#pragma unroll
      for (int m = 0; m < 6; ++m) {
        a  += dot4(wAr[u][m], hreg[m]);
        bv += dot4(wBr[u][m], hreg[m]);
      }
#pragma unroll
      for (int mm = 8; mm; mm >>= 1) {
        a  += __shfl_xor(a, mm);
        bv += __shfl_xor(bv, mm);
      }
      if (lane == 0) {
        if (r < NRW_) { PA[r * 97 + (i - 1)] = a; PB[r * 97 + (i - 1)] = bv; }
        else if (ENC && r == 42) sh_aknew = a;
      }
    }
    __syncthreads();

    // ---- attention weights, pre-scaled by s (3-barrier softmax) ----
    if (ENC) {
      if (tid == 0) alpha[i - 1] = sh_aknew;
      float av = -3.0e38f;
      if (tid < i) {
        float ak = (tid == i - 1) ? sh_aknew : alpha[tid];
        av = ak - (1.0f - pf_mrow) * 1e30f;
      }
      float v = av;
#pragma unroll
      for (int m = 32; m; m >>= 1) v = fmaxf(v, __shfl_xor(v, m));
      if ((tid & 63) == 0) red4a[tid >> 6] = v;
      __syncthreads();
      float mx = fmaxf(fmaxf(red4a[0], red4a[1]), fmaxf(red4a[2], red4a[3]));
      float e = (tid < i) ? expf(av - mx) : 0.0f;
      v = e;
#pragma unroll
      for (int m = 32; m; m >>= 1) v += __shfl_xor(v, m);
      if ((tid & 63) == 0) red4b[tid >> 6] = v;
      __syncthreads();
      float ssum = red4b[0] + red4b[1] + red4b[2] + red4b[3];
      if (tid < N_) {
        float w = (tid < i) ? e / ssum : 0.0f;
        float sv = s_sm[tid];
        ws0[tid] = w * sv;
        ws1[tid] = w - w * sv;
        if (sl == 0) p.adjB[((size_t)b * N_ + i) * N_ + tid] = w;
      }
      __syncthreads();
    } else {
      if (tid < N_) {
        float w = (tid < i) ? -pf_mrow : 0.0f;
        float sv = s_sm[tid];
        ws0[tid] = w * sv;
        ws1[tid] = w - w * sv;
      }
      __syncthreads();
    }

    // ---- dots[r] = sum_n ws0[n]*PA[r][n] + ws1[n]*PB[r][n] ----
    {
      float wsr0[6], wsr1[6];
#pragma unroll
      for (int k = 0; k < 6; ++k) {
        wsr0[k] = ws0[lane + 16*k];
        wsr1[k] = ws1[lane + 16*k];
      }
#pragma unroll
      for (int u = 0; u < 3; ++u) {
        const int r = team + 16 * u;
        if (r < NRW_) {
          float acc = 0.f;
#pragma unroll
          for (int k = 0; k < 6; ++k) {
            int n = lane + 16*k;
            acc = fmaf(wsr0[k], PA[r * 97 + n], fmaf(wsr1[k], PB[r * 97 + n], acc));
          }
#pragma unroll
          for (int mm = 8; mm; mm >>= 1) acc += __shfl_xor(acc, mm);
          if (lane == 0) dots[r] = acc;
        }
      }
    }
    __syncthreads();

    // ---- combine gates, publish hn ----
    if (tid < SD_) {
      int j = j0 + tid;
      float Mj = dots[36 + tid];
      float rc = sigf(pf_gi0 + dots[tid] + bh0);
      float zc = sigf(pf_gi1 + dots[6 + tid] + bh1);
      float nc = tanhf(pf_gi2 + rc * (dots[12 + tid] + bh2));
      float outc = (1.0f - zc) * nc + zc * Mj;
      float rp = sigf(dots[18 + tid] + bi0 + pf_gh0);
      float zp = sigf(dots[24 + tid] + bi1 + pf_gh1);
      float np = tanhf(dots[30 + tid] + bi2 + rp * pf_gh2);
      float hv = outc + (1.0f - zp) * np + zp * pf_q;
      p.bufC[((size_t)b * N_ + i) * CONC_ + j] = hv;
      atstf(&p.hnX[((size_t)b * N_ + i) * HID_ + j], hv);
    }
    __syncthreads();   // protect stage[]/dots before next iteration
  }
#undef BULK_STAGE
}

// ---------------- feature_map = I - adjB2 (row 0 implicit 0) ----------------
__global__ __launch_bounds__(256)
void fmap_kernel(const float* __restrict__ adjB2, float* __restrict__ out)
{
  int idx = blockIdx.x * 256 + threadIdx.x;
  if (idx < B_ * N_ * N_) {
    int j = idx % N_;
    int i = (idx / N_) % N_;
    float a = (i == 0) ? 0.0f : adjB2[idx];
    out[idx] = ((i == j) ? 1.0f : 0.0f) - a;
  }
}

// ---------------- orchestration ----------------
extern "C" void kernel_launch(void* const* d_in, const int* in_sizes, int n_in,
                              void* d_out, int out_size, void* d_ws, size_t ws_size,
                              hipStream_t stream)
{
  (void)in_sizes; (void)n_in; (void)out_size; (void)ws_size;
  const float* features     = (const float*)d_in[0];
  const float* adj          = (const float*)d_in[1];
  const float* s_mask       = (const float*)d_in[2];
  const float* enc_fc1_W    = (const float*)d_in[5];
  const float* enc_fc1_b    = (const float*)d_in[6];
  const float* enc_gat_w    = (const float*)d_in[7];
  const float* enc_Wr0      = (const float*)d_in[9];
  const float* enc_Wr1      = (const float*)d_in[10];
  const float* enc_gruc_Wih = (const float*)d_in[11];
  const float* enc_gruc_Whh = (const float*)d_in[12];
  const float* enc_gruc_bih = (const float*)d_in[13];
  const float* enc_gruc_bhh = (const float*)d_in[14];
  const float* enc_grup_Wih = (const float*)d_in[15];
  const float* enc_grup_Whh = (const float*)d_in[16];
  const float* enc_grup_bih = (const float*)d_in[17];
  const float* enc_grup_bhh = (const float*)d_in[18];
  const float* enc_mlp_W0   = (const float*)d_in[19];
  const float* enc_mlp_b0   = (const float*)d_in[20];
  const float* enc_mlp_W1   = (const float*)d_in[21];
  const float* enc_mlp_b1   = (const float*)d_in[22];
  const float* dec_fc1_W    = (const float*)d_in[23];
  const float* dec_fc1_b    = (const float*)d_in[24];
  const float* dec_Wr0      = (const float*)d_in[25];
  const float* dec_Wr1      = (const float*)d_in[26];
  const float* dec_gruc_Wih = (const float*)d_in[27];
  const float* dec_gruc_Whh = (const float*)d_in[28];
  const float* dec_gruc_bih = (const float*)d_in[29];
  const float* dec_gruc_bhh = (const float*)d_in[30];
  const float* dec_grup_Wih = (const float*)d_in[31];
  const float* dec_grup_Whh = (const float*)d_in[32];
  const float* dec_grup_bih = (const float*)d_in[33];
  const float* dec_grup_bhh = (const float*)d_in[34];
  const float* dec_mlp_W0   = (const float*)d_in[35];
  const float* dec_mlp_b0   = (const float*)d_in[36];
  const float* dec_mlp_W1   = (const float*)d_in[37];
  const float* dec_mlp_b1   = (const float*)d_in[38];

  float* ws = (float*)d_ws;
  size_t o = 0;
  float* Hse   = ws + o; o += (size_t)B_ * N_ * CONC_;
  float* Hsd   = ws + o; o += (size_t)B_ * N_ * CONC_;
  float* GIc   = ws + o; o += (size_t)B_ * N_ * GID_;
  float* GHp   = ws + o; o += (size_t)B_ * N_ * GID_;
  float* adjB1 = ws + o; o += (size_t)B_ * N_ * N_;
  float* adjB2 = ws + o; o += (size_t)B_ * N_ * N_;
  float* fU    = ws + o; o += (size_t)B_ * N_ * CODE_;
  float* Tmp   = ws + o; o += (size_t)B_ * N_ * HID_;
  float* hnX4  = ws + o; o += (size_t)4 * B_ * N_ * HID_;   // one per scan
  float* Gbuf  = ws + o; o += (size_t)4 * GID_ * HID_;
  const size_t hn_elems = (size_t)B_ * N_ * HID_;

  const dim3 blk(256);
  float* logits = (float*)d_out;
  float* fmap   = (float*)d_out + (size_t)B_ * N_ * FEAT_;

  // sentinel-fill ALL four per-scan exchange buffers once
  hipMemsetAsync(hnX4, 0xFF, 4 * hn_elems * sizeof(float), stream);

  // encoder fc1
  gemm_bias<1><<<dim3(6, 12), blk, 0, stream>>>(features, EMB_, enc_fc1_W, enc_fc1_b,
                                                Hse, CONC_, EMB_);
  // encoder scans
  for (int l = 0; l < 2; ++l) {
    const float* Hl = Hse + l * HID_;
    gemm_bias2<<<dim3(18, 12, 2), blk, 0, stream>>>(Hl,
        enc_gruc_Wih + (size_t)l * GID_ * HID_, enc_gruc_bih + l * GID_, GIc,
        enc_grup_Whh + (size_t)l * GID_ * HID_, enc_grup_bhh + l * GID_, GHp);
    prod_kernel<<<dim3(6, 18, 4), blk, 0, stream>>>(
        enc_gruc_Whh + (size_t)l * GID_ * HID_, enc_grup_Wih + (size_t)l * GID_ * HID_,
        enc_Wr0 + (size_t)l * HID_ * HID_, enc_Wr1 + (size_t)l * HID_ * HID_, Gbuf);
    ScanP p;
    p.Hl = Hl; p.bufC = Hse + (l + 1) * HID_;
    p.hnX = hnX4 + (size_t)l * hn_elems; p.G = Gbuf;
    p.GIc = GIc; p.GHp = GHp;
    p.bhhc = enc_gruc_bhh + l * GID_;
    p.bihp = enc_grup_bih + l * GID_;
    p.Wr0 = enc_Wr0 + (size_t)l * HID_ * HID_;
    p.Wr1 = enc_Wr1 + (size_t)l * HID_ * HID_;
    p.wk = enc_gat_w + l * 2 * HID_ + HID_;
    p.mask = adj; p.smask = s_mask;
    p.adjB = (l == 0) ? adjB1 : adjB2;
    scan_kernel<1><<<dim3(512), blk, 0, stream>>>(p);
  }
  // encoder MLP -> fU
  gemm_bias<1><<<dim3(6, 12), blk, 0, stream>>>(Hse, CONC_, enc_mlp_W0, enc_mlp_b0,
                                                Tmp, HID_, CONC_);
  gemm_bias<0><<<dim3(3, 12), blk, 0, stream>>>(Tmp, HID_, enc_mlp_W1, enc_mlp_b1,
                                                fU, CODE_, HID_);
  // decoder fc1
  gemm_bias<1><<<dim3(6, 12), blk, 0, stream>>>(fU, CODE_, dec_fc1_W, dec_fc1_b,
                                                Hsd, CONC_, CODE_);
  // decoder scans
  for (int l = 0; l < 2; ++l) {
    const float* Hl = Hsd + l * HID_;
    gemm_bias2<<<dim3(18, 12, 2), blk, 0, stream>>>(Hl,
        dec_gruc_Wih + (size_t)l * GID_ * HID_, dec_gruc_bih + l * GID_, GIc,
        dec_grup_Whh + (size_t)l * GID_ * HID_, dec_grup_bhh + l * GID_, GHp);
    prod_kernel<<<dim3(6, 18, 4), blk, 0, stream>>>(
        dec_gruc_Whh + (size_t)l * GID_ * HID_, dec_grup_Wih + (size_t)l * GID_ * HID_,
        dec_Wr0 + (size_t)l * HID_ * HID_, dec_Wr1 + (size_t)l * HID_ * HID_, Gbuf);
    ScanP p;
    p.Hl = Hl; p.bufC = Hsd + (l + 1) * HID_;
    p.hnX = hnX4 + (size_t)(2 + l) * hn_elems; p.G = Gbuf;
    p.GIc = GIc; p.GHp = GHp;
    p.bhhc = dec_gruc_bhh + l * GID_;
    p.bihp = dec_grup_bih + l * GID_;
    p.Wr0 = dec_Wr0 + (size_t)l * HID_ * HID_;
    p.Wr1 = dec_Wr1 + (size_t)l * HID_ * HID_;
    p.wk = nullptr;
    p.mask = (l == 0) ? adjB1 : adjB2;   // w[n] = -adjB[b,i,n] for n<i
    p.smask = s_mask;
    p.adjB = nullptr;
    scan_kernel<0><<<dim3(512), blk, 0, stream>>>(p);
  }
  // decoder MLP -> logits
  gemm_bias<1><<<dim3(6, 12), blk, 0, stream>>>(Hsd, CONC_, dec_mlp_W0, dec_mlp_b0,
                                                Tmp, HID_, CONC_);
  gemm_bias<0><<<dim3(12, 12), blk, 0, stream>>>(Tmp, HID_, dec_mlp_W1, dec_mlp_b1,
                                                 logits, FEAT_, HID_);
  // feature_map
  fmap_kernel<<<dim3((B_ * N_ * N_ + 255) / 256), blk, 0, stream>>>(adjB2, fmap);
}